// Round 2
// baseline (13.975 us; speedup 1.0000x reference)
//
#include <hip/hip_runtime.h>

// NeuS renderer: per-ray alpha compositing over D=128 depth samples.
// sdf_grid:   (B, D, H, W)    float32
// color_grid: (B, 3, D, H, W) float32
// variance:   scalar float32
// out: color (B,3,H,W) flat, then weights_sum (B,1,H,W) flat.
//
// One thread per ray (b,h,w); consecutive threads (consecutive w) are adjacent
// in memory at every depth d -> fully coalesced.
//
// Depth loop is chunked by CH=8: all 8 sdf + 24 color loads for a chunk are
// issued before any compute (no data-dependent branch between them), so HBM
// latency is paid ~2x per wave instead of ~15x. Early exit (trans < 1e-6)
// only at chunk boundaries; truncation error bounded by 1e-6 (colors in [0,1]).

#define BB 2
#define DD 128
#define HH 256
#define WW 256
#define CH 8

__global__ __launch_bounds__(256) void neus_render_kernel(
    const float* __restrict__ sdf_grid,
    const float* __restrict__ color_grid,
    const float* __restrict__ variance,
    float* __restrict__ out)
{
    const int NHW = HH * WW;                       // 65536
    const int idx = blockIdx.x * blockDim.x + threadIdx.x;
    if (idx >= BB * NHW) return;
    const int b  = idx / NHW;
    const int hw = idx - b * NHW;

    const float inv_s = __expf(variance[0] * 10.0f);

    const size_t dstride = (size_t)NHW;            // stride between depth samples
    const size_t cstride = (size_t)DD * NHW;       // stride between color channels

    const float* __restrict__ sdf = sdf_grid   + (size_t)b * DD * NHW + hw;
    const float* __restrict__ col = color_grid + (size_t)b * 3 * DD * NHW + hw;

    float trans = 1.0f;
    float c0 = 0.0f, c1 = 0.0f, c2 = 0.0f, wsum = 0.0f;

    float prev_cdf = 1.0f / (1.0f + __expf(-sdf[0] * inv_s));

    // d = 0 .. 126 (127 iterations), chunks of CH
    for (int d0 = 0; d0 < DD - 1; d0 += CH) {
        float s[CH], r[CH], g[CH], bl[CH];
        // --- issue all loads for the chunk (clamped in-bounds, no branches) ---
        #pragma unroll
        for (int j = 0; j < CH; ++j) {
            int d  = d0 + j;
            int dc = d < DD - 1 ? d : DD - 2;      // clamp (in-bounds, masked later)
            s[j]  = sdf[(size_t)(dc + 1) * dstride];
            r[j]  = col[(size_t)dc * dstride];
            g[j]  = col[cstride + (size_t)dc * dstride];
            bl[j] = col[2 * cstride + (size_t)dc * dstride];
        }
        // --- compute the chunk ---
        #pragma unroll
        for (int j = 0; j < CH; ++j) {
            int d = d0 + j;
            float next_cdf = 1.0f / (1.0f + __expf(-s[j] * inv_s));
            if (d < DD - 1) {
                float alpha = (prev_cdf - next_cdf + 1e-5f) / (prev_cdf + 1e-5f);
                alpha = fminf(fmaxf(alpha, 0.0f), 1.0f);
                float w = alpha * trans;
                wsum += w;
                c0 += r[j]  * w;
                c1 += g[j]  * w;
                c2 += bl[j] * w;
                trans *= (1.0f - alpha + 1e-7f);
                prev_cdf = next_cdf;
            }
        }
        if (trans < 1e-6f) break;   // bounded truncation error <= 1e-6
    }

    // Outputs: color (B,3,H,W) then weights_sum (B,1,H,W), concatenated flat.
    out[((size_t)b * 3 + 0) * NHW + hw] = c0;
    out[((size_t)b * 3 + 1) * NHW + hw] = c1;
    out[((size_t)b * 3 + 2) * NHW + hw] = c2;
    out[(size_t)BB * 3 * NHW + (size_t)b * NHW + hw] = wsum;
}

extern "C" void kernel_launch(void* const* d_in, const int* in_sizes, int n_in,
                              void* d_out, int out_size, void* d_ws, size_t ws_size,
                              hipStream_t stream)
{
    const float* sdf_grid   = (const float*)d_in[0];
    const float* color_grid = (const float*)d_in[1];
    const float* variance   = (const float*)d_in[2];
    float* out = (float*)d_out;

    const int total = BB * HH * WW;                // 131072 rays
    dim3 block(256);
    dim3 grid((total + 255) / 256);                // 512 blocks
    neus_render_kernel<<<grid, block, 0, stream>>>(sdf_grid, color_grid, variance, out);
}